// Round 7
// baseline (244.429 us; speedup 1.0000x reference)
//
#include <hip/hip_runtime.h>
#include <math.h>

// B=8192 rows, F=3072 features, block=3.
//
// v6 (resubmit — R6 bench died to container infra, no signal): v1's winning
// one-shot structure (high-churn grid, no persistence, no LDS staging, plain
// stores) but 2 rows per WG with ALL 12 dwordx4 loads issued before any
// compute. Evidence: v1/v2/v5 pinned 88-95 us at ~3 TB/s aggregate L2
// traffic with nothing saturated; copy ubench does 6.3 TB/s -> testing the
// aggregate memory-level-parallelism model (time ~ traffic /
// (outstanding-bytes-per-CU / latency)). Doubling per-wave in-flight bytes
// at equal occupancy should cut time ~proportionally if that model is right.
// Row-A compute waits vmcnt(6); row-B loads stay in flight underneath.
#define BATCH 8192
#define FEAT  3072
#define TPB   256
#define RPG   2                  // rows per one-shot WG
#define NWG   (BATCH / RPG)      // 4096
#define RS4   (FEAT / 4)         // row stride in float4s

// Analytic log|det J| for the d=3 Moebius block:
//   T(z) = w + (1-|w|^2)(z+w)/|z+w|^2 is conformal, DT = lambda*(I-2nn^T),
//   lambda = (1-|w|^2)/|z+w|^2 = c. For y = r*T(x/r): |det J| = c^(d-1) = c^2.
//   sum log|det| = 2*ln2 * sum log2(c).

__global__ __launch_bounds__(TPB, 8)
void moebius_kernel(const float* __restrict__ x,
                    const float* __restrict__ w,
                    float* __restrict__ out) {
    __shared__ float swred[TPB / 64][RPG];

    const int tid  = threadIdx.x;
    const int lane = tid & 63;
    const int wave = tid >> 6;
    const size_t row0 = (size_t)blockIdx.x * RPG;
    const size_t base = row0 * FEAT + 12 * tid;   // 12 contiguous floats/row

    const float4* __restrict__ x4 = (const float4*)(x + base);
    const float4* __restrict__ w4 = (const float4*)(w + base);
    float4* __restrict__ y4       = (float4*)(out + base);

    // All 12 independent 16B loads issued up front: 12 KB/wave in flight.
    float4 xv[RPG][3], wv[RPG][3];
    #pragma unroll
    for (int rr = 0; rr < RPG; ++rr) {
        #pragma unroll
        for (int k = 0; k < 3; ++k) {
            xv[rr][k] = x4[rr * RS4 + k];
            wv[rr][k] = w4[rr * RS4 + k];
        }
    }

    #pragma unroll
    for (int rr = 0; rr < RPG; ++rr) {
        const float4 xa = xv[rr][0], xb = xv[rr][1], xc = xv[rr][2];
        const float4 wa = wv[rr][0], wb = wv[rr][1], wc = wv[rr][2];
        const float X[12] = {xa.x, xa.y, xa.z, xa.w, xb.x, xb.y, xb.z, xb.w,
                             xc.x, xc.y, xc.z, xc.w};
        const float W[12] = {wa.x, wa.y, wa.z, wa.w, wb.x, wb.y, wb.z, wb.w,
                             wc.x, wc.y, wc.z, wc.w};
        float Y[12];
        float lsum = 0.0f;   // accumulates log2(c)

        #pragma unroll
        for (int j = 0; j < 4; ++j) {
            const float x0 = X[3 * j], x1 = X[3 * j + 1], x2 = X[3 * j + 2];
            const float w0 = W[3 * j], w1 = W[3 * j + 1], w2 = W[3 * j + 2];

            // fmaxf guard: numerically inert for real inputs but blocks the
            // only inf->NaN path (rsq(0)=inf, 0*inf=NaN).
            const float r2   = fmaxf(x0 * x0 + x1 * x1 + x2 * x2, 1e-30f);
            const float invr = __builtin_amdgcn_rsqf(r2);   // 1/|x|
            const float r    = r2 * invr;                   // |x|

            const float p0 = x0 * invr + w0;
            const float p1 = x1 * invr + w1;
            const float p2 = x2 * invr + w2;

            const float wns  = w0 * w0 + w1 * w1 + w2 * w2;
            const float xwns = fmaxf(p0 * p0 + p1 * p1 + p2 * p2, 1e-30f);
            const float cc   = (1.0f - wns) * __builtin_amdgcn_rcpf(xwns);

            Y[3 * j]     = r * (cc * p0 + w0);
            Y[3 * j + 1] = r * (cc * p1 + w1);
            Y[3 * j + 2] = r * (cc * p2 + w2);

            lsum += __builtin_amdgcn_logf(cc);   // log2(c)
        }

        y4[rr * RS4 + 0] = make_float4(Y[0], Y[1], Y[2],  Y[3]);
        y4[rr * RS4 + 1] = make_float4(Y[4], Y[5], Y[6],  Y[7]);
        y4[rr * RS4 + 2] = make_float4(Y[8], Y[9], Y[10], Y[11]);

        // Per-row wave reduction (no barrier yet).
        #pragma unroll
        for (int off = 32; off > 0; off >>= 1) {
            lsum += __shfl_down(lsum, off, 64);
        }
        if (lane == 0) swred[wave][rr] = lsum;
    }

    __syncthreads();   // single barrier per WG
    if (tid < RPG) {
        const float tot = (swred[0][tid] + swred[1][tid] +
                           swred[2][tid] + swred[3][tid]) * 1.3862943611f;
        out[(size_t)BATCH * FEAT + row0 + tid] = tot;
    }
}

extern "C" void kernel_launch(void* const* d_in, const int* in_sizes, int n_in,
                              void* d_out, int out_size, void* d_ws, size_t ws_size,
                              hipStream_t stream) {
    const float* x = (const float*)d_in[0];
    const float* w = (const float*)d_in[1];
    float* out = (float*)d_out;   // [B*F] y followed by [B] log_det_J

    moebius_kernel<<<NWG, TPB, 0, stream>>>(x, w, out);
}